// Round 5
// baseline (2451.721 us; speedup 1.0000x reference)
//
#include <hip/hip_runtime.h>
#include <hip/hip_fp16.h>
#include <math.h>

#define B_   512
#define C_   3
#define T_   500
#define D_   40
#define CD_  120
#define N_   256
#define OUT_ 12
#define TILE 8
#define NTILE 63        // 63*8 = 504 >= 500

// ws layout: W1T fp32 [120][256] at float offset 0, then fp16 region:
//   W2iT_h [257][256], W2rT_h [257][256]  (row 256 = zeros for pad indices)
#define W1T_F    30720
#define W2I_H_OFF 0
#define W2R_H_OFF 65792

// ---------------- prep ----------------
__global__ void prep_kernel(const float* __restrict__ W1, const float* __restrict__ W2i,
                            const float* __restrict__ W2r, float* __restrict__ ws) {
    __half* wsh = (__half*)(ws + W1T_F);
    int i = blockIdx.x * 256 + threadIdx.x;   // 0 .. 257*256-1
    int k = i >> 8, n = i & 255;
    if (k < 256) {
        wsh[W2I_H_OFF + i] = __float2half(W2i[n * 256 + k]);
        wsh[W2R_H_OFF + i] = __float2half(W2r[n * 256 + k]);
    } else if (k == 256) {
        wsh[W2I_H_OFF + i] = __float2half(0.f);
        wsh[W2R_H_OFF + i] = __float2half(0.f);
    }
    if (i < CD_ * N_) ws[i] = W1[n * CD_ + k];     // W1T[k][n]
}

// ---------------- ALIF update (exact reference order) ----------------
__device__ __forceinline__ void alif_step(float I, float& m, float& s, float& a,
                                          float al, float rh) {
    a = rh * a + (1.f - rh) * s;
    float Bth = 0.01f + 1.8f * a;
    m = al * m + (1.f - al) * I - Bth * s;
    s = ((m - Bth) > 0.f) ? 1.f : 0.f;
}

// one padded segment list (fp16 table), 16 loads in flight (cnt multiple of 8)
__device__ __forceinline__ void gather16h(const __half* __restrict__ Wt,
                                          const int* __restrict__ L,
                                          const float2* __restrict__ M,
                                          int cnt, int n, float& g0, float& g1) {
    int j = 0;
    for (; j + 16 <= cnt; j += 16) {
        int4 ia = *(const int4*)(L + j);
        int4 ib = *(const int4*)(L + j + 4);
        int4 ic = *(const int4*)(L + j + 8);
        int4 id = *(const int4*)(L + j + 12);
        float4 ma = *(const float4*)(M + j);
        float4 mb = *(const float4*)(M + j + 2);
        float4 mc = *(const float4*)(M + j + 4);
        float4 md = *(const float4*)(M + j + 6);
        float4 me = *(const float4*)(M + j + 8);
        float4 mf = *(const float4*)(M + j + 10);
        float4 mg = *(const float4*)(M + j + 12);
        float4 mh = *(const float4*)(M + j + 14);
        float w0  = __half2float(Wt[(ia.x << 8) + n]);
        float w1  = __half2float(Wt[(ia.y << 8) + n]);
        float w2  = __half2float(Wt[(ia.z << 8) + n]);
        float w3  = __half2float(Wt[(ia.w << 8) + n]);
        float w4  = __half2float(Wt[(ib.x << 8) + n]);
        float w5  = __half2float(Wt[(ib.y << 8) + n]);
        float w6  = __half2float(Wt[(ib.z << 8) + n]);
        float w7  = __half2float(Wt[(ib.w << 8) + n]);
        float w8  = __half2float(Wt[(ic.x << 8) + n]);
        float w9  = __half2float(Wt[(ic.y << 8) + n]);
        float w10 = __half2float(Wt[(ic.z << 8) + n]);
        float w11 = __half2float(Wt[(ic.w << 8) + n]);
        float w12 = __half2float(Wt[(id.x << 8) + n]);
        float w13 = __half2float(Wt[(id.y << 8) + n]);
        float w14 = __half2float(Wt[(id.z << 8) + n]);
        float w15 = __half2float(Wt[(id.w << 8) + n]);
        g0 += w0*ma.x;  g1 += w0*ma.y;  g0 += w1*ma.z;  g1 += w1*ma.w;
        g0 += w2*mb.x;  g1 += w2*mb.y;  g0 += w3*mb.z;  g1 += w3*mb.w;
        g0 += w4*mc.x;  g1 += w4*mc.y;  g0 += w5*mc.z;  g1 += w5*mc.w;
        g0 += w6*md.x;  g1 += w6*md.y;  g0 += w7*md.z;  g1 += w7*md.w;
        g0 += w8*me.x;  g1 += w8*me.y;  g0 += w9*me.z;  g1 += w9*me.w;
        g0 += w10*mf.x; g1 += w10*mf.y; g0 += w11*mf.z; g1 += w11*mf.w;
        g0 += w12*mg.x; g1 += w12*mg.y; g0 += w13*mg.z; g1 += w13*mg.w;
        g0 += w14*mh.x; g1 += w14*mh.y; g0 += w15*mh.z; g1 += w15*mh.w;
    }
    if (j < cnt) {
        int4 ia = *(const int4*)(L + j);
        int4 ib = *(const int4*)(L + j + 4);
        float4 ma = *(const float4*)(M + j);
        float4 mb = *(const float4*)(M + j + 2);
        float4 mc = *(const float4*)(M + j + 4);
        float4 md = *(const float4*)(M + j + 6);
        float w0 = __half2float(Wt[(ia.x << 8) + n]);
        float w1 = __half2float(Wt[(ia.y << 8) + n]);
        float w2 = __half2float(Wt[(ia.z << 8) + n]);
        float w3 = __half2float(Wt[(ia.w << 8) + n]);
        float w4 = __half2float(Wt[(ib.x << 8) + n]);
        float w5 = __half2float(Wt[(ib.y << 8) + n]);
        float w6 = __half2float(Wt[(ib.z << 8) + n]);
        float w7 = __half2float(Wt[(ib.w << 8) + n]);
        g0 += w0*ma.x; g1 += w0*ma.y; g0 += w1*ma.z; g1 += w1*ma.w;
        g0 += w2*mb.x; g1 += w2*mb.y; g0 += w3*mb.z; g1 += w3*mb.w;
        g0 += w4*mc.x; g1 += w4*mc.y; g0 += w5*mc.z; g1 += w5*mc.w;
        g0 += w6*md.x; g1 += w6*md.y; g0 += w7*md.z; g1 += w7*md.w;
    }
}

// --- full scan: 2 batch rows / WG, 1024 threads = 4 k-quarters, role-specialized ---
// q0: layer-1 ALIF + list1.  q1: layer-2 ALIF + list2 + P/S.  all: i1 tile + gather.
__global__ __launch_bounds__(1024, 1) void scan_kernel(
    const float* __restrict__ x, const float* __restrict__ thr_p,
    const float* __restrict__ b1, const float* __restrict__ b2i,
    const float* __restrict__ b2r, const float* __restrict__ b3,
    const float* __restrict__ tau_adp1, const float* __restrict__ tau_m1,
    const float* __restrict__ tau_adp2, const float* __restrict__ tau_m2,
    const float* __restrict__ tau_m3, const float* __restrict__ W3,
    const float* __restrict__ ws, float* __restrict__ out) {

    __shared__ float xsf_t[2][TILE][CD_];                 // [g][tt][k] staging
    __shared__ __align__(16) float xsf8[2][CD_][TILE];    // [g][k][tt]
    __shared__ float i1s[2][TILE][N_];                    // i1 tile results
    __shared__ __align__(16) int    idx1[2][4][72];
    __shared__ __align__(16) int    idx2[2][4][72];
    __shared__ __align__(16) float2 mf1[2][4][72];
    __shared__ __align__(16) float2 mf2[2][4][72];
    __shared__ int cw1[2][4], cw2[2][4];
    __shared__ float part[4][2][N_];                      // [quarter][row][n]
    __shared__ float red[2][OUT_][4];
    __shared__ float accs_l[2][OUT_];

    const int tid  = threadIdx.x;        // 0..1023
    const int n    = tid & 255;          // neuron
    const int h    = tid >> 8;           // quarter 0..3 (gathers segment h)
    const int seg  = (tid >> 6) & 3;     // wave index within quarter
    const int lane = tid & 63;
    const int b0   = blockIdx.x * 2;

    const float* W1T = ws;
    const __half* wsh  = (const __half*)(ws + W1T_F);
    const __half* W2iH = wsh + W2I_H_OFF;
    const __half* W2rH = wsh + W2R_H_OFF;

    const float thrv = thr_p[0];
    const float al1 = expf(-1.0f / tau_m1[n]);
    const float rh1 = expf(-1.0f / tau_adp1[n]);
    const float al2 = expf(-1.0f / tau_m2[n]);
    const float rh2 = expf(-1.0f / tau_adp2[n]);
    const float b1v = b1[n];
    const float b2v = b2i[n] + b2r[n];

    float al3j[OUT_];
    #pragma unroll
    for (int o = 0; o < OUT_; ++o) al3j[o] = expf(-1.0f / tau_m3[o]);

    // recurrent state: layer1 live only in q0, layer2 + P/S only in q1
    float m1[2] = {0.f, 0.f}, s1f[2] = {0.f, 0.f}, a1v[2] = {0.01f, 0.01f};
    float m2[2] = {0.f, 0.f}, s2f[2] = {0.f, 0.f}, a2v[2] = {0.01f, 0.01f};
    float S[2] = {0.f, 0.f};
    float P[2][OUT_];
    #pragma unroll
    for (int g = 0; g < 2; ++g)
        #pragma unroll
        for (int o = 0; o < OUT_; ++o) P[g][o] = 0.f;

    if (tid < 4) cw2[1][tid] = 0;        // t=0 reads parity 1: empty
    const unsigned long long lmask = (1ull << lane) - 1ull;

    // i1 tile role: quarter h computes combos (g = h&1, tt in [tb*4, tb*4+4))
    const int gq = h & 1, tb = h >> 1;

    // x staging: 1920 elems over 1024 threads
    float xreg[2];
    #pragma unroll
    for (int j = 0; j < 2; ++j) {
        int idx = tid + j * 1024;
        if (idx < 2 * TILE * CD_) {
            int g = idx / (TILE * CD_), r = idx % (TILE * CD_);
            int tt = r / CD_, k = r % CD_;
            int c = k / D_, d = k - c * D_;
            int tg = tt; if (tg > T_ - 1) tg = T_ - 1;
            xreg[j] = x[((b0 + g) * C_ + c) * (T_ * D_) + tg * D_ + d];
        }
    }

    #pragma unroll 1
    for (int it = 0; it < NTILE; ++it) {
        const int t0 = it * TILE;

        #pragma unroll
        for (int j = 0; j < 2; ++j) {
            int idx = tid + j * 1024;
            if (idx < 2 * TILE * CD_) {
                int g = idx / (TILE * CD_), r = idx % (TILE * CD_);
                int tt = r / CD_, k = r % CD_;
                float xv = xreg[j];
                float tp = ((xv - thrv)  > 0.f) ? 1.f : 0.f;
                float tn = ((-thrv - xv) > 0.f) ? 1.f : 0.f;
                xsf_t[g][tt][k] = tp - tn;
            }
        }
        __syncthreads();                                   // T1

        if (it + 1 < NTILE) {                              // prefetch next tile
            const int t0n = (it + 1) * TILE;
            #pragma unroll
            for (int j = 0; j < 2; ++j) {
                int idx = tid + j * 1024;
                if (idx < 2 * TILE * CD_) {
                    int g = idx / (TILE * CD_), r = idx % (TILE * CD_);
                    int tt = r / CD_, k = r % CD_;
                    int c = k / D_, d = k - c * D_;
                    int tg = t0n + tt; if (tg > T_ - 1) tg = T_ - 1;
                    xreg[j] = x[((b0 + g) * C_ + c) * (T_ * D_) + tg * D_ + d];
                }
            }
        }

        #pragma unroll
        for (int j = 0; j < 2; ++j) {                      // transpose
            int idx = tid + j * 1024;
            if (idx < 2 * TILE * CD_) {
                int g = idx / (TILE * CD_), r = idx % (TILE * CD_);
                int k = r / TILE, tt = r % TILE;
                xsf8[g][k][tt] = xsf_t[g][tt][k];
            }
        }
        __syncthreads();                                   // T2

        // ---- i1 tile: quarter h computes 4 (g,tt) combos; total work 1x ----
        {
            float acc0 = 0.f, acc1 = 0.f, acc2 = 0.f, acc3 = 0.f;
            const float* wc = W1T + n;
            #pragma unroll 4
            for (int k = 0; k < CD_; ++k) {
                float w = wc[k << 8];
                float4 xa = *(const float4*)&xsf8[gq][k][tb * 4];
                acc0 += xa.x * w; acc1 += xa.y * w;
                acc2 += xa.z * w; acc3 += xa.w * w;
            }
            i1s[gq][tb * 4 + 0][n] = acc0;
            i1s[gq][tb * 4 + 1][n] = acc1;
            i1s[gq][tb * 4 + 2][n] = acc2;
            i1s[gq][tb * 4 + 3][n] = acc3;
        }
        __syncthreads();                                   // T3

        // ---- 8 steps ----
        #pragma unroll
        for (int tt = 0; tt < TILE; ++tt) {
            const int t = t0 + tt;
            const int pp = t & 1, pq = pp ^ 1;

            if (h == 0) {          // layer-1 ALIF + union list1 (wave-uniform guard)
                alif_step(b1v + i1s[0][tt][n], m1[0], s1f[0], a1v[0], al1, rh1);
                alif_step(b1v + i1s[1][tt][n], m1[1], s1f[1], a1v[1], al1, rh1);
                bool p0 = s1f[0] > 0.5f, p1 = s1f[1] > 0.5f;
                unsigned long long bu = __ballot(p0) | __ballot(p1);
                int cnt = __popcll(bu), cpad = (cnt + 7) & ~7;
                if (p0 | p1) {
                    int r = __popcll(bu & lmask);
                    idx1[pp][seg][r] = n;
                    mf1[pp][seg][r] = make_float2(p0 ? 1.f : 0.f, p1 ? 1.f : 0.f);
                } else {
                    int nr = __popcll(~bu & lmask);
                    if (nr < cpad - cnt) {
                        idx1[pp][seg][cnt + nr] = 256;
                        mf1[pp][seg][cnt + nr] = make_float2(0.f, 0.f);
                    }
                }
                if (lane == 0) cw1[pp][seg] = cpad;
            }
            __syncthreads();                               // B1: list1 ready

            // all threads: gather segment h of both lists
            float g0 = 0.f, g1 = 0.f;
            gather16h(W2iH, &idx1[pp][h][0], &mf1[pp][h][0], cw1[pp][h], n, g0, g1);
            gather16h(W2rH, &idx2[pq][h][0], &mf2[pq][h][0], cw2[pq][h], n, g0, g1);
            part[h][0][n] = g0;
            part[h][1][n] = g1;
            __syncthreads();                               // B2: partials ready

            if (h == 1) {          // layer-2 ALIF + union list2 + P/S
                float i20 = b2v + ((part[0][0][n] + part[1][0][n]) +
                                   (part[2][0][n] + part[3][0][n]));
                float i21 = b2v + ((part[0][1][n] + part[1][1][n]) +
                                   (part[2][1][n] + part[3][1][n]));
                alif_step(i20, m2[0], s2f[0], a2v[0], al2, rh2);
                alif_step(i21, m2[1], s2f[1], a2v[1], al2, rh2);
                bool p0 = s2f[0] > 0.5f, p1 = s2f[1] > 0.5f;
                unsigned long long bu = __ballot(p0) | __ballot(p1);
                int cnt = __popcll(bu), cpad = (cnt + 7) & ~7;
                if (p0 | p1) {
                    int r = __popcll(bu & lmask);
                    idx2[pp][seg][r] = n;
                    mf2[pp][seg][r] = make_float2(p0 ? 1.f : 0.f, p1 ? 1.f : 0.f);
                } else {
                    int nr = __popcll(~bu & lmask);
                    if (nr < cpad - cnt) {
                        idx2[pp][seg][cnt + nr] = 256;
                        mf2[pp][seg][cnt + nr] = make_float2(0.f, 0.f);
                    }
                }
                if (lane == 0) cw2[pp][seg] = cpad;
                if (t < T_) {
                    S[0] += s2f[0]; S[1] += s2f[1];
                    #pragma unroll
                    for (int o = 0; o < OUT_; ++o) {
                        P[0][o] = al3j[o] * (P[0][o] + s2f[0]);
                        P[1][o] = al3j[o] * (P[1][o] + s2f[1]);
                    }
                }
            }
        }
        __syncthreads();   // tile end: lists/parts consumed before xsf_t rewrite
    }

    // ---- epilogue (q1 holds S,P): acc = W3·(S-P) + b3*C_o ; log_softmax ----
    if (h == 1) {
        #pragma unroll
        for (int g = 0; g < 2; ++g) {
            #pragma unroll
            for (int o = 0; o < OUT_; ++o) {
                float v = W3[o * N_ + n] * (S[g] - P[g][o]);
                v += __shfl_down(v, 32);
                v += __shfl_down(v, 16);
                v += __shfl_down(v, 8);
                v += __shfl_down(v, 4);
                v += __shfl_down(v, 2);
                v += __shfl_down(v, 1);
                if (lane == 0) red[g][o][seg] = v;
            }
        }
    }
    __syncthreads();
    if (tid < 24) {
        int g = tid / OUT_, o = tid % OUT_;
        float acc = red[g][o][0] + red[g][o][1] + red[g][o][2] + red[g][o][3];
        float al3 = al3j[o];
        float alT = expf(-(float)T_ / tau_m3[o]);
        float Co  = (float)T_ - al3 * (1.f - alT) / (1.f - al3);
        acc += b3[o] * Co;
        accs_l[g][o] = acc / (float)T_;
    }
    __syncthreads();
    if (tid < 24) {
        int g = tid / OUT_, o = tid % OUT_;
        float mx = -1e30f;
        #pragma unroll
        for (int o2 = 0; o2 < OUT_; ++o2) mx = fmaxf(mx, accs_l[g][o2]);
        float se = 0.f;
        #pragma unroll
        for (int o2 = 0; o2 < OUT_; ++o2) se += expf(accs_l[g][o2] - mx);
        out[(b0 + g) * OUT_ + o] = accs_l[g][o] - mx - logf(se);
    }
}

// ---------------- host ----------------
extern "C" void kernel_launch(void* const* d_in, const int* in_sizes, int n_in,
                              void* d_out, int out_size, void* d_ws, size_t ws_size,
                              hipStream_t stream) {
    (void)in_sizes; (void)n_in; (void)out_size; (void)ws_size;
    const float* x        = (const float*)d_in[0];
    const float* thr      = (const float*)d_in[1];
    const float* W1       = (const float*)d_in[2];
    const float* b1       = (const float*)d_in[3];
    const float* W2_in    = (const float*)d_in[4];
    const float* b2_in    = (const float*)d_in[5];
    const float* W2_rec   = (const float*)d_in[6];
    const float* b2_rec   = (const float*)d_in[7];
    const float* W3       = (const float*)d_in[8];
    const float* b3       = (const float*)d_in[9];
    const float* tau_adp1 = (const float*)d_in[10];
    const float* tau_m1   = (const float*)d_in[11];
    const float* tau_adp2 = (const float*)d_in[12];
    const float* tau_m2   = (const float*)d_in[13];
    const float* tau_m3   = (const float*)d_in[14];
    float* ws  = (float*)d_ws;
    float* out = (float*)d_out;

    prep_kernel<<<257, 256, 0, stream>>>(W1, W2_in, W2_rec, ws);
    scan_kernel<<<B_ / 2, 1024, 0, stream>>>(x, thr, b1, b2_in, b2_rec, b3,
                                             tau_adp1, tau_m1, tau_adp2, tau_m2,
                                             tau_m3, W3, ws, out);
}

// Round 6
// 1740.914 us; speedup vs baseline: 1.4083x; 1.4083x over previous
//
#include <hip/hip_runtime.h>
#include <math.h>

#define B_   512
#define T_   500
#define C_   3
#define D_   40
#define CD_  120
#define N_   256
#define OUT_ 12
#define G_   16          // batch rows per block -> 32 blocks

typedef __attribute__((ext_vector_type(8))) short short8;   // 8 x bf16 (4 VGPRs)
typedef __attribute__((ext_vector_type(4))) float f32x4;    // MFMA accumulator

// ws (ushort units): bf16 B-fragment tables.
// Frag layout (verified mapping): B[k][n], n = nt*16+(lane&15), k = kt*32+(lane>>4)*8+j
// element index = ((kt*16+nt)*64 + lane)*8 + j
#define W2IN_F  0        // kt<8, nt<16  -> 65536
#define W2REC_F 65536    // kt<8, nt<16  -> 65536
#define W1_F    131072   // kt<4, nt<16  -> 32768 (k>=120 zero)
#define W3_F    163840   // kt<8, single nt (cols=OUT pad 16) -> 4096

__device__ __forceinline__ unsigned short f2bf(float v) {
    unsigned x = __float_as_uint(v);
    unsigned r = (x + 0x7fffu + ((x >> 16) & 1u)) >> 16;   // round-nearest-even
    return (unsigned short)r;
}

// ---------------- prep: build bf16 B-fragment tables in ws ----------------
__global__ void prep_kernel(const float* __restrict__ W1, const float* __restrict__ W2i,
                            const float* __restrict__ W2r, const float* __restrict__ W3,
                            unsigned short* __restrict__ wsu) {
    int i = blockIdx.x * 256 + threadIdx.x;          // 0..167935 exactly
    if (i < 131072) {
        int r = i & 65535;
        int j = r & 7, lane = (r >> 3) & 63, nt = (r >> 9) & 15, kt = r >> 13;
        int n = nt * 16 + (lane & 15);
        int k = kt * 32 + ((lane >> 4) << 3) + j;
        const float* W = (i < 65536) ? W2i : W2r;
        wsu[i] = f2bf(W[n * 256 + k]);
    } else if (i < 163840) {
        int r = i - 131072;
        int j = r & 7, lane = (r >> 3) & 63, nt = (r >> 9) & 15, kt = r >> 13;  // kt<4
        int n = nt * 16 + (lane & 15);
        int k = kt * 32 + ((lane >> 4) << 3) + j;
        wsu[i] = (k < CD_) ? f2bf(W1[n * CD_ + k]) : (unsigned short)0;
    } else {
        int r = i - 163840;                          // 0..4095
        int j = r & 7, lane = (r >> 3) & 63, kt = r >> 9;    // kt<8
        int o = lane & 15;
        int k = kt * 32 + ((lane >> 4) << 3) + j;
        wsu[i] = (o < OUT_) ? f2bf(W3[o * 256 + k]) : (unsigned short)0;
    }
}

// ---------------- full scan: 16 batch rows / block, MFMA everywhere ----------------
__global__ __launch_bounds__(512, 2) void scan_kernel(
    const float* __restrict__ x, const float* __restrict__ thr_p,
    const float* __restrict__ b1, const float* __restrict__ b2i,
    const float* __restrict__ b2r, const float* __restrict__ b3,
    const float* __restrict__ tau_adp1, const float* __restrict__ tau_m1,
    const float* __restrict__ tau_adp2, const float* __restrict__ tau_m2,
    const float* __restrict__ tau_m3,
    const unsigned short* __restrict__ wsu, float* __restrict__ out) {

    __shared__ __align__(16) unsigned short w2in_lds[65536];  // 128 KB, frag layout
    __shared__ __align__(16) unsigned short s1A[4096];        // A-frag layout [kt][lane][8]
    __shared__ __align__(16) unsigned short s2A[4096];
    __shared__ __align__(16) unsigned short xsA[4096];        // [t'][kt<4][lane][8]

    const int tid  = threadIdx.x;
    const int wave = tid >> 6, lane = tid & 63;
    const int l15  = lane & 15, qd = lane >> 4;
    const int b0   = blockIdx.x * G_;
    const int nt0  = wave * 2, nt1 = nt0 + 1;

    // ---- prolog: W2in -> LDS; zero s2A and xsA pad slots ----
    {
        const short8* src = (const short8*)(wsu + W2IN_F);
        short8* dst = (short8*)w2in_lds;
        #pragma unroll
        for (int i = 0; i < 16; ++i) dst[tid + i * 512] = src[tid + i * 512];
    }
    {
        short8 z = {0, 0, 0, 0, 0, 0, 0, 0};
        ((short8*)s2A)[tid] = z;                      // 512 * 16B = whole s2A
        if (tid >= 480) {                             // xsA (kt=3,q=3) zero pad, written once
            int idx = tid - 480, tp = idx >> 4, row = idx & 15;
            *(short8*)&xsA[((tp * 4 + 3) * 64 + 48 + row) * 8] = z;
        }
    }
    // persistent B-frags: W1 (all waves), W3 (wave 7)
    short8 w1b[2][4];
    #pragma unroll
    for (int i = 0; i < 2; ++i)
        #pragma unroll
        for (int kt = 0; kt < 4; ++kt)
            w1b[i][kt] = *(const short8*)&wsu[W1_F + ((kt * 16 + nt0 + i) * 64 + lane) * 8];
    short8 w3b[8] = {};
    if (wave == 7) {
        #pragma unroll
        for (int kt = 0; kt < 8; ++kt)
            w3b[kt] = *(const short8*)&wsu[W3_F + (kt * 64 + lane) * 8];
    }

    // per-column ALIF params (col = neuron n = nt*16 + l15)
    const float thrv = thr_p[0];
    float p_al1[2], p_rh1[2], p_b1[2], p_al2[2], p_rh2[2], p_b2[2];
    #pragma unroll
    for (int i = 0; i < 2; ++i) {
        int n = (nt0 + i) * 16 + l15;
        p_al1[i] = expf(-1.0f / tau_m1[n]);
        p_rh1[i] = expf(-1.0f / tau_adp1[n]);
        p_al2[i] = expf(-1.0f / tau_m2[n]);
        p_rh2[i] = expf(-1.0f / tau_adp2[n]);
        p_b1[i]  = b1[n];
        p_b2[i]  = b2i[n] + b2r[n];
    }
    const int oi = (l15 < OUT_) ? l15 : 0;
    const float p_al3 = expf(-1.0f / tau_m3[oi]);
    const float p_b3  = (l15 < OUT_) ? b3[l15] : 0.f;

    // x staging roles: threads 0..479 each own (t'=tid/240, row, k-octet)
    const bool stg = (tid < 480);
    int sc_t = 0, sc_off = 0;
    const float* px = x;
    if (stg) {
        sc_t = tid / 240; int srr = tid % 240;
        int row = srr / 15, oct = srr % 15, k0 = oct * 8;
        int c = k0 / D_, d = k0 % D_;
        px = x + ((size_t)(b0 + row) * C_ + c) * (size_t)(T_ * D_) + d;
        sc_off = ((sc_t * 4 + (k0 >> 5)) * 64 + ((k0 >> 3) & 3) * 16 + row) * 8;
    }

    float4 xr0 = {0,0,0,0}, xr1 = {0,0,0,0};
    if (stg) { const float* p = px + (size_t)sc_t * D_;          // tile 0
               xr0 = *(const float4*)p; xr1 = *(const float4*)(p + 4); }
    __syncthreads();                       // LDS copy/zero complete

    // stage tile 0
    if (stg) {
        float tf[8];
        *(float4*)&tf[0] = xr0; *(float4*)&tf[4] = xr1;
        __align__(16) unsigned short tu[8];
        #pragma unroll
        for (int j = 0; j < 8; ++j)
            tu[j] = ((tf[j] - thrv) > 0.f) ? (unsigned short)0x3F80
                  : (((-thrv - tf[j]) > 0.f) ? (unsigned short)0xBF80 : (unsigned short)0);
        *(short8*)&xsA[sc_off] = *(const short8*)tu;
    }
    __syncthreads();

    // i1 MFMA tile 0 -> i1c regs
    float i1c[2][2][4];
    #pragma unroll
    for (int tp = 0; tp < 2; ++tp) {
        f32x4 d0 = {0.f,0.f,0.f,0.f}, d1 = d0;
        #pragma unroll
        for (int kt = 0; kt < 4; ++kt) {
            short8 ax = *(const short8*)&xsA[((tp * 4 + kt) * 64 + lane) * 8];
            d0 = __builtin_amdgcn_mfma_f32_16x16x32_bf16(ax, w1b[0][kt], d0, 0, 0, 0);
            d1 = __builtin_amdgcn_mfma_f32_16x16x32_bf16(ax, w1b[1][kt], d1, 0, 0, 0);
        }
        #pragma unroll
        for (int r = 0; r < 4; ++r) { i1c[tp][0][r] = d0[r]; i1c[tp][1][r] = d1[r]; }
    }
    // prefetch tile 1 (global steps 2+sc_t)
    if (stg) { const float* p = px + (size_t)(2 + sc_t) * D_;
               xr0 = *(const float4*)p; xr1 = *(const float4*)(p + 4); }

    // recurrent state in C-layout regs: (row = qd*4+r, col = nt_i*16+l15)
    float m1s[8] = {0,0,0,0,0,0,0,0}, s1s[8] = {0,0,0,0,0,0,0,0}, a1s[8];
    float m2s[8] = {0,0,0,0,0,0,0,0}, s2s[8] = {0,0,0,0,0,0,0,0}, a2s[8];
    #pragma unroll
    for (int i = 0; i < 8; ++i) { a1s[i] = 0.01f; a2s[i] = 0.01f; }
    float m3v[4] = {0,0,0,0}, accv[4] = {0,0,0,0};
    float i2v[8];

    #pragma unroll 1
    for (int t = 0; t < T_; ++t) {
        // ---- P0: layer-1 ALIF + s1 -> A-frag layout in LDS ----
        {
            const int tp = t & 1;
            #pragma unroll
            for (int i = 0; i < 2; ++i) {
                const int nt = nt0 + i;
                const int koff = ((nt >> 1) * 64 + (((nt & 1) << 1) | (l15 >> 3)) * 16) * 8 + (l15 & 7);
                #pragma unroll
                for (int r = 0; r < 4; ++r) {
                    const int idx = i * 4 + r;
                    float I = p_b1[i] + i1c[tp][i][r];
                    a1s[idx] = p_rh1[i] * a1s[idx] + (1.f - p_rh1[i]) * s1s[idx];
                    float Bth = 0.01f + 1.8f * a1s[idx];
                    m1s[idx] = p_al1[i] * m1s[idx] + (1.f - p_al1[i]) * I - Bth * s1s[idx];
                    s1s[idx] = ((m1s[idx] - Bth) > 0.f) ? 1.f : 0.f;
                    s1A[koff + (qd * 4 + r) * 8] = (s1s[idx] > 0.5f) ? (unsigned short)0x3F80
                                                                     : (unsigned short)0;
                }
            }
        }
        __syncthreads();                                   // B1

        // ---- P1: i2 MFMA (W2in from LDS, W2rec from L2) + i3 (w7) + next-tile i1 (odd) ----
        {
            f32x4 c0 = {0.f,0.f,0.f,0.f}, c1 = c0, c3 = c0;
            const unsigned short* w2r_g = wsu + W2REC_F;
            #pragma unroll
            for (int kt = 0; kt < 8; ++kt) {
                short8 a1f = *(const short8*)&s1A[(kt * 64 + lane) * 8];
                short8 a2f = *(const short8*)&s2A[(kt * 64 + lane) * 8];
                short8 bi0 = *(const short8*)&w2in_lds[((kt * 16 + nt0) * 64 + lane) * 8];
                short8 bi1 = *(const short8*)&w2in_lds[((kt * 16 + nt1) * 64 + lane) * 8];
                short8 br0 = *(const short8*)&w2r_g[((kt * 16 + nt0) * 64 + lane) * 8];
                short8 br1 = *(const short8*)&w2r_g[((kt * 16 + nt1) * 64 + lane) * 8];
                c0 = __builtin_amdgcn_mfma_f32_16x16x32_bf16(a1f, bi0, c0, 0, 0, 0);
                c1 = __builtin_amdgcn_mfma_f32_16x16x32_bf16(a1f, bi1, c1, 0, 0, 0);
                c0 = __builtin_amdgcn_mfma_f32_16x16x32_bf16(a2f, br0, c0, 0, 0, 0);
                c1 = __builtin_amdgcn_mfma_f32_16x16x32_bf16(a2f, br1, c1, 0, 0, 0);
                if (wave == 7)
                    c3 = __builtin_amdgcn_mfma_f32_16x16x32_bf16(a2f, w3b[kt], c3, 0, 0, 0);
            }
            #pragma unroll
            for (int r = 0; r < 4; ++r) { i2v[r] = c0[r]; i2v[4 + r] = c1[r]; }
            if (wave == 7 && t > 0) {                      // lagged layer-3 (step t-1)
                #pragma unroll
                for (int r = 0; r < 4; ++r) {
                    m3v[r] = p_al3 * m3v[r] + (1.f - p_al3) * (c3[r] + p_b3);
                    accv[r] += m3v[r];
                }
            }
            if ((t & 1) && t < T_ - 1) {                   // i1 for next tile
                #pragma unroll
                for (int tp = 0; tp < 2; ++tp) {
                    f32x4 d0 = {0.f,0.f,0.f,0.f}, d1 = d0;
                    #pragma unroll
                    for (int kt = 0; kt < 4; ++kt) {
                        short8 ax = *(const short8*)&xsA[((tp * 4 + kt) * 64 + lane) * 8];
                        d0 = __builtin_amdgcn_mfma_f32_16x16x32_bf16(ax, w1b[0][kt], d0, 0, 0, 0);
                        d1 = __builtin_amdgcn_mfma_f32_16x16x32_bf16(ax, w1b[1][kt], d1, 0, 0, 0);
                    }
                    #pragma unroll
                    for (int r = 0; r < 4; ++r) { i1c[tp][0][r] = d0[r]; i1c[tp][1][r] = d1[r]; }
                }
            }
        }
        __syncthreads();                                   // B2

        // ---- P2: layer-2 ALIF + s2 -> A-frag LDS; even t: stage next tile + prefetch ----
        {
            #pragma unroll
            for (int i = 0; i < 2; ++i) {
                const int nt = nt0 + i;
                const int koff = ((nt >> 1) * 64 + (((nt & 1) << 1) | (l15 >> 3)) * 16) * 8 + (l15 & 7);
                #pragma unroll
                for (int r = 0; r < 4; ++r) {
                    const int idx = i * 4 + r;
                    float I = p_b2[i] + i2v[idx];
                    a2s[idx] = p_rh2[i] * a2s[idx] + (1.f - p_rh2[i]) * s2s[idx];
                    float Bth = 0.01f + 1.8f * a2s[idx];
                    m2s[idx] = p_al2[i] * m2s[idx] + (1.f - p_al2[i]) * I - Bth * s2s[idx];
                    s2s[idx] = ((m2s[idx] - Bth) > 0.f) ? 1.f : 0.f;
                    s2A[koff + (qd * 4 + r) * 8] = (s2s[idx] > 0.5f) ? (unsigned short)0x3F80
                                                                     : (unsigned short)0;
                }
            }
            if (!(t & 1) && t < T_ - 2 && stg) {           // stage tile t/2+1 from regs
                float tf[8];
                *(float4*)&tf[0] = xr0; *(float4*)&tf[4] = xr1;
                __align__(16) unsigned short tu[8];
                #pragma unroll
                for (int j = 0; j < 8; ++j)
                    tu[j] = ((tf[j] - thrv) > 0.f) ? (unsigned short)0x3F80
                          : (((-thrv - tf[j]) > 0.f) ? (unsigned short)0xBF80 : (unsigned short)0);
                *(short8*)&xsA[sc_off] = *(const short8*)tu;
                if (t <= T_ - 6) {                         // prefetch global step t+4+sc_t
                    const float* p = px + (size_t)(t + 4 + sc_t) * D_;
                    xr0 = *(const float4*)p; xr1 = *(const float4*)(p + 4);
                }
            }
        }
        __syncthreads();                                   // B3
    }

    // ---- flush layer-3 for step T-1, then log_softmax + store (wave 7) ----
    if (wave == 7) {
        f32x4 c3 = {0.f,0.f,0.f,0.f};
        #pragma unroll
        for (int kt = 0; kt < 8; ++kt) {
            short8 a2f = *(const short8*)&s2A[(kt * 64 + lane) * 8];
            c3 = __builtin_amdgcn_mfma_f32_16x16x32_bf16(a2f, w3b[kt], c3, 0, 0, 0);
        }
        #pragma unroll
        for (int r = 0; r < 4; ++r) {
            m3v[r] = p_al3 * m3v[r] + (1.f - p_al3) * (c3[r] + p_b3);
            accv[r] += m3v[r];
        }
        #pragma unroll
        for (int r = 0; r < 4; ++r) {
            float L = accv[r] / (float)T_;
            float mx = (l15 < OUT_) ? L : -1e30f;
            #pragma unroll
            for (int off = 1; off < 16; off <<= 1)
                mx = fmaxf(mx, __shfl_xor(mx, off, 16));
            float e = (l15 < OUT_) ? expf(L - mx) : 0.f;
            float se = e;
            #pragma unroll
            for (int off = 1; off < 16; off <<= 1)
                se += __shfl_xor(se, off, 16);
            if (l15 < OUT_)
                out[(size_t)(b0 + qd * 4 + r) * OUT_ + l15] = L - mx - logf(se);
        }
    }
}

// ---------------- host ----------------
extern "C" void kernel_launch(void* const* d_in, const int* in_sizes, int n_in,
                              void* d_out, int out_size, void* d_ws, size_t ws_size,
                              hipStream_t stream) {
    (void)in_sizes; (void)n_in; (void)out_size; (void)ws_size;
    const float* x        = (const float*)d_in[0];
    const float* thr      = (const float*)d_in[1];
    const float* W1       = (const float*)d_in[2];
    const float* b1       = (const float*)d_in[3];
    const float* W2_in    = (const float*)d_in[4];
    const float* b2_in    = (const float*)d_in[5];
    const float* W2_rec   = (const float*)d_in[6];
    const float* b2_rec   = (const float*)d_in[7];
    const float* W3       = (const float*)d_in[8];
    const float* b3       = (const float*)d_in[9];
    const float* tau_adp1 = (const float*)d_in[10];
    const float* tau_m1   = (const float*)d_in[11];
    const float* tau_adp2 = (const float*)d_in[12];
    const float* tau_m2   = (const float*)d_in[13];
    const float* tau_m3   = (const float*)d_in[14];
    unsigned short* wsu = (unsigned short*)d_ws;
    float* out = (float*)d_out;

    prep_kernel<<<656, 256, 0, stream>>>(W1, W2_in, W2_rec, W3, wsu);
    scan_kernel<<<B_ / G_, 512, 0, stream>>>(x, thr, b1, b2_in, b2_rec, b3,
                                             tau_adp1, tau_m1, tau_adp2, tau_m2,
                                             tau_m3, wsu, out);
}